// Round 2
// baseline (301.753 us; speedup 1.0000x reference)
//
#include <hip/hip_runtime.h>
#include <hip/hip_bf16.h>

#define NN 100000
#define NE 1600000
#define NB 391        // ceil(NN/256) buckets, bucket = col >> 8
#define EPB 3125      // edges per block in scatter: 512 blocks x 3125 = NE exactly
#define NBLK 512
#define CAP 4608      // fixed bucket capacity = 9*512: Poisson(4092)+8 sigma

// NOTE (r10/r12 postmortem): intra-kernel grid-wide barriers cost ~120 µs on
// gfx950 (cross-XCD visibility). Split dispatches win.
// NOTE (r1): 391/512-block grids co-schedule 3-4 blocks/CU -> block-count
// rounding is NOT a sink (r0 prediction missed). This round: delete the CSR
// sort entirely; prop passes consume unsorted buckets via LDS float atomics
// (edge-balanced, 9 gathers in flight/thread).

// ---- prep: edge-dtype detect + weight folding + bucket cursor init -------

__global__ __launch_bounds__(256) void prep_kernel(
    const unsigned int* __restrict__ ew, int* __restrict__ is64,
    const float* __restrict__ W1, const float* __restrict__ b1,
    const float* __restrict__ W2, const float* __restrict__ b2,
    const float* __restrict__ W3, const float* __restrict__ b3,
    const float* __restrict__ W4, const float* __restrict__ b4,
    const float* __restrict__ W5, const float* __restrict__ b5,
    float* __restrict__ Wt, float* __restrict__ cv,
    int* __restrict__ bcursor) {
    __shared__ int nz;
    __shared__ float w45[32 * 3], w345[32 * 3], w2345[32 * 3];
    int tid = threadIdx.x;
    if (tid == 0) nz = 0;
    __syncthreads();
    // int64 staging ⇒ odd 32-bit words are all-zero high words (values < 2^31)
    if (ew[2 * tid + 1] != 0) atomicAdd(&nz, 1);
    for (int i = tid; i < NB; i += 256) bcursor[i] = i * CAP;
    int i = tid / 3, j = tid - 3 * (tid / 3);
    if (tid < 96) {
        float s = 0.0f;
        for (int k = 0; k < 32; k++) s += W4[i * 32 + k] * W5[k * 3 + j];
        w45[i * 3 + j] = s;
    }
    __syncthreads();
    if (tid < 96) {
        float s = 0.0f;
        for (int k = 0; k < 32; k++) s += W3[i * 32 + k] * w45[k * 3 + j];
        w345[i * 3 + j] = s;
    }
    __syncthreads();
    if (tid < 96) {
        float s = 0.0f;
        for (int k = 0; k < 32; k++) s += W2[i * 32 + k] * w345[k * 3 + j];
        w2345[i * 3 + j] = s;
    }
    __syncthreads();
    if (tid < 32) {
        int ii = tid >> 2, jj = tid & 3;  // 8 x 4
        float s = 0.0f;
        if (jj < 3)
            for (int k = 0; k < 32; k++) s += W1[ii * 32 + k] * w2345[k * 3 + jj];
        Wt[tid] = s;
    }
    if (tid >= 32 && tid < 52) {
        int kk = (tid - 32) >> 2, jj = (tid - 32) & 3;  // 5 x 4
        float s = 0.0f;
        if (jj < 3) {
            if (kk == 0) for (int k = 0; k < 32; k++) s += b1[k] * w2345[k * 3 + jj];
            if (kk == 1) for (int k = 0; k < 32; k++) s += b2[k] * w345[k * 3 + jj];
            if (kk == 2) for (int k = 0; k < 32; k++) s += b3[k] * w45[k * 3 + jj];
            if (kk == 3) for (int k = 0; k < 32; k++) s += b4[k] * W5[k * 3 + jj];
            if (kk == 4) s = b5[jj];
        }
        cv[tid - 32] = s;
    }
    if (tid == 0) *is64 = (nz == 0) ? 1 : 0;
}

// ---- scatter: 512 threads, EPB=3125 (512 blocks) -------------------------
// epacked[i] = (col&255)<<24 | row (row < 2^24); bucket regions fixed CAP.

__global__ __launch_bounds__(512) void bucket_scatter_kernel(const void* __restrict__ ei,
                                                             const int* __restrict__ is64,
                                                             int* __restrict__ bcursor,
                                                             unsigned int* __restrict__ epacked) {
    __shared__ int lcount[NB];
    __shared__ int lstart[NB];
    __shared__ int lcur[NB];
    __shared__ int gbase[NB];
    __shared__ int wsum[8];
    __shared__ unsigned int slotv[EPB];
    __shared__ unsigned short slotb[EPB];
    int tid = threadIdx.x;
    for (int i = tid; i < NB; i += 512) lcount[i] = 0;
    __syncthreads();
    int f = *is64;
    int base = blockIdx.x * EPB;  // NBLK*EPB == NE: no bounds guards needed
    int r[7], c[7];
    r[6] = -1;
    if (f == 0) {
        const int* e32 = (const int*)ei;
#pragma unroll
        for (int k = 0; k < 6; k++) {
            int e = base + k * 512 + tid;
            r[k] = e32[e];
            c[k] = e32[NE + e];
        }
        if (tid < EPB - 6 * 512) {
            int e = base + 6 * 512 + tid;
            r[6] = e32[e];
            c[6] = e32[NE + e];
        }
    } else {
        const long long* e64 = (const long long*)ei;
#pragma unroll
        for (int k = 0; k < 6; k++) {
            int e = base + k * 512 + tid;
            r[k] = (int)e64[e];
            c[k] = (int)e64[(long long)NE + e];
        }
        if (tid < EPB - 6 * 512) {
            int e = base + 6 * 512 + tid;
            r[6] = (int)e64[e];
            c[6] = (int)e64[(long long)NE + e];
        }
    }
#pragma unroll
    for (int k = 0; k < 7; k++)
        if (r[k] >= 0) atomicAdd(&lcount[c[k] >> 8], 1);
    __syncthreads();
    // exclusive scan of lcount over 512-wide via wave shuffles (8 waves)
    int lane = tid & 63, w = tid >> 6;
    int v = (tid < NB) ? lcount[tid] : 0;
    int acc = v;
#pragma unroll
    for (int off = 1; off < 64; off <<= 1) {
        int y = __shfl_up(acc, off);
        if (lane >= off) acc += y;
    }
    if (lane == 63) wsum[w] = acc;
    __syncthreads();
    if (tid == 0) {
        int s = 0;
#pragma unroll
        for (int j = 0; j < 8; j++) { int t = wsum[j]; wsum[j] = s; s += t; }
    }
    __syncthreads();
    acc += wsum[w];
    if (tid < NB) {
        int excl = acc - v;
        lstart[tid] = excl;
        lcur[tid] = excl;
    }
    // reserve global slices, one atomic per touched bucket
    for (int i = tid; i < NB; i += 512) {
        int cnt = lcount[i];
        gbase[i] = cnt ? atomicAdd(&bcursor[i], cnt) : 0;
    }
    __syncthreads();
    // group edges by bucket in LDS
#pragma unroll
    for (int k = 0; k < 7; k++) {
        if (r[k] >= 0) {
            int b = c[k] >> 8;
            int pos = atomicAdd(&lcur[b], 1);
            slotv[pos] = ((unsigned)(c[k] & 255) << 24) | (unsigned)r[k];
            slotb[pos] = (unsigned short)b;
        }
    }
    __syncthreads();
    // coalesced-ish flush (runs of same bucket are contiguous)
    for (int s2 = tid; s2 < EPB; s2 += 512) {
        int b = slotb[s2];
        int dst = gbase[b] + (s2 - lstart[b]);
        if (dst < (b + 1) * CAP) epacked[dst] = slotv[s2];  // overflow guard (8-sigma)
    }
}

// ---- deg_z: per-bucket degree count + dinv + fused z (no sort, no srow) --

__global__ __launch_bounds__(512) void deg_z_kernel(const unsigned int* __restrict__ epacked,
                                                    const int* __restrict__ bcursor,
                                                    const float* __restrict__ x,
                                                    const float* __restrict__ Wt,
                                                    float* __restrict__ dinv,
                                                    float4* __restrict__ Ta, int N) {
    __shared__ int lcount[256];
    __shared__ float4 Wl[8];
    int b = blockIdx.x;
    int tid = threadIdx.x;
    if (tid < 8) Wl[tid] = ((const float4*)Wt)[tid];
    if (tid < 256) lcount[tid] = 0;
    int s0 = b * CAP;
    int cnt = bcursor[b] - s0;
    if (cnt > CAP) cnt = CAP;
    __syncthreads();
    for (int i = tid; i < cnt; i += 512)
        atomicAdd(&lcount[epacked[s0 + i] >> 24], 1);
    __syncthreads();
    if (tid < 256) {
        int col = (b << 8) + tid;
        if (col < N) {
            float d = 1.0f / sqrtf((float)lcount[tid] + 1.0f);  // +1 self-loop
            dinv[col] = d;
            // z: t0 = d * (x[col] @ Wt)
            const float4* x4 = (const float4*)x + col * 2;
            float4 av = x4[0], bv = x4[1];
            float xs[8] = {av.x, av.y, av.z, av.w, bv.x, bv.y, bv.z, bv.w};
            float4 o = make_float4(0.f, 0.f, 0.f, 0.f);
#pragma unroll
            for (int k = 0; k < 8; k++) {
                float4 ww = Wl[k];
                o.x += xs[k] * ww.x; o.y += xs[k] * ww.y; o.z += xs[k] * ww.z;
            }
            o.x *= d; o.y *= d; o.z *= d; o.w = 0.0f;
            Ta[col] = o;
        }
    }
}

// ---- propagation: one block per bucket, unsorted edges, LDS float atomics.
//      a[c] = t[c] + Σ_{(r,c)∈bucket} t[r];  LAST: out = d*a + c5,
//      else t' = d*d*a + d*ck.  9 gathers in flight per thread (CAP=9*512).

template <bool LAST>
__global__ __launch_bounds__(512) void prop_kernel(
    const unsigned int* __restrict__ epacked, const int* __restrict__ bcursor,
    const float* __restrict__ dinv, const float4* __restrict__ tin,
    const float* __restrict__ cv, int kk,
    float4* __restrict__ tout, float* __restrict__ out, int N) {
    __shared__ float acc[768];
    int b = blockIdx.x;
    int tid = threadIdx.x;
    for (int i = tid; i < 768; i += 512) acc[i] = 0.0f;
    int s0 = b * CAP;
    int cnt = bcursor[b] - s0;
    if (cnt > CAP) cnt = CAP;
    __syncthreads();
    if (cnt > 0) {  // uniform branch
        int last = s0 + cnt - 1;
        unsigned int ev[9];
        float4 vv[9];
#pragma unroll
        for (int k = 0; k < 9; k++) {           // 9 independent coalesced loads
            int i = s0 + k * 512 + tid;
            ev[k] = epacked[i < last ? i : last];
        }
#pragma unroll
        for (int k = 0; k < 9; k++)             // 9 independent gathers (L2-resident)
            vv[k] = tin[ev[k] & 0xFFFFFFu];
#pragma unroll
        for (int k = 0; k < 9; k++) {
            if (k * 512 + tid < cnt) {
                int c3 = (int)(ev[k] >> 24) * 3;
                atomicAdd(&acc[c3 + 0], vv[k].x);
                atomicAdd(&acc[c3 + 1], vv[k].y);
                atomicAdd(&acc[c3 + 2], vv[k].z);
            }
        }
    }
    __syncthreads();
    if (tid < 256) {
        int col = (b << 8) + tid;
        if (col < N) {
            float4 t = tin[col];                 // self-loop
            float ax = acc[tid * 3 + 0] + t.x;
            float ay = acc[tid * 3 + 1] + t.y;
            float az = acc[tid * 3 + 2] + t.z;
            float dd = dinv[col];
            float cx = cv[kk * 4 + 0], cy = cv[kk * 4 + 1], cz = cv[kk * 4 + 2];
            if (LAST) {
                out[col * 3 + 0] = dd * ax + cx;
                out[col * 3 + 1] = dd * ay + cy;
                out[col * 3 + 2] = dd * az + cz;
            } else {
                float d2 = dd * dd;
                tout[col] = make_float4(d2 * ax + dd * cx, d2 * ay + dd * cy,
                                        d2 * az + dd * cz, 0.0f);
            }
        }
    }
}

// ---- launch --------------------------------------------------------------

extern "C" void kernel_launch(void* const* d_in, const int* in_sizes, int n_in,
                              void* d_out, int out_size, void* d_ws, size_t ws_size,
                              hipStream_t stream) {
    const float* x  = (const float*)d_in[0];
    const void*  ei = d_in[1];
    const float* W1 = (const float*)d_in[2];  const float* b1 = (const float*)d_in[3];
    const float* W2 = (const float*)d_in[4];  const float* b2 = (const float*)d_in[5];
    const float* W3 = (const float*)d_in[6];  const float* b3 = (const float*)d_in[7];
    const float* W4 = (const float*)d_in[8];  const float* b4 = (const float*)d_in[9];
    const float* W5 = (const float*)d_in[10]; const float* b5 = (const float*)d_in[11];
    float* out = (float*)d_out;

    char* p = (char*)d_ws;
    auto alloc = [&](size_t bytes) {
        char* r = p;
        p += (bytes + 255) & ~(size_t)255;
        return r;
    };
    float* dinv    = (float*)alloc((size_t)NN * 4);
    int*   is64    = (int*)alloc(256);
    int*   bcursor = (int*)alloc(NB * 4);
    float* Wt      = (float*)alloc(8 * 4 * 4);
    float* cv      = (float*)alloc(5 * 4 * 4);
    unsigned int* epacked = (unsigned int*)alloc((size_t)NB * CAP * 4);
    float4*       Ta      = (float4*)alloc((size_t)NN * 16);
    float4*       Tb      = (float4*)alloc((size_t)NN * 16);
    if ((size_t)(p - (char*)d_ws) > ws_size) return;  // canary: zero output

    prep_kernel<<<1, 256, 0, stream>>>((const unsigned int*)ei, is64,
                                       W1, b1, W2, b2, W3, b3, W4, b4, W5, b5,
                                       Wt, cv, bcursor);
    bucket_scatter_kernel<<<NBLK, 512, 0, stream>>>(ei, is64, bcursor, epacked);
    deg_z_kernel<<<NB, 512, 0, stream>>>(epacked, bcursor, x, Wt, dinv, Ta, NN);

    // g_k = Â g_{k-1} + 1 c_k^T in folded t = dinv ⊙ g coordinates
    prop_kernel<false><<<NB, 512, 0, stream>>>(epacked, bcursor, dinv, Ta, cv, 0, Tb, nullptr, NN);
    prop_kernel<false><<<NB, 512, 0, stream>>>(epacked, bcursor, dinv, Tb, cv, 1, Ta, nullptr, NN);
    prop_kernel<false><<<NB, 512, 0, stream>>>(epacked, bcursor, dinv, Ta, cv, 2, Tb, nullptr, NN);
    prop_kernel<false><<<NB, 512, 0, stream>>>(epacked, bcursor, dinv, Tb, cv, 3, Ta, nullptr, NN);
    prop_kernel<true><<<NB, 512, 0, stream>>>(epacked, bcursor, dinv, Ta, cv, 4, nullptr, out, NN);
}

// Round 3
// 173.296 us; speedup vs baseline: 1.7413x; 1.7413x over previous
//
#include <hip/hip_runtime.h>

#define NN 100000
#define NE 1600000
#define NB 391        // ceil(NN/256) buckets, bucket = col >> 8
#define EPB 3125      // edges per block in scatter: 512 blocks x 3125 = NE exactly
#define NBLK 512
#define CAP 4608      // fixed bucket capacity: Poisson(4092)+8 sigma

// NOTE (r10/r12 postmortem): intra-kernel grid-wide barriers cost ~120 µs on
// gfx950 (cross-XCD visibility). Split dispatches win.
// NOTE (r1): block-count rounding (391 vs 512) is NOT a sink — 3-4 blocks/CU
// co-schedule. NOTE (r2): unsorted-edge prop via LDS float atomics is ~+27
// µs/pass WORSE than CSR prop + shuffle reduce. CSR structure restored.
// This round: scatter loses scan/grouping/flush (direct scattered stores);
// csr reads epacked ONCE into registers; prep deleted (folding in csr,
// per-wave dtype ballot in scatter, bcursor via hipMemsetAsync).

// ---- scatter: count -> reserve -> direct scattered store -----------------
// epacked[i] = (col&255)<<24 | row (row < 2^24); bucket regions fixed CAP.
// bcursor[b] holds COUNT (base b*CAP added locally); memset to 0 before.

__global__ __launch_bounds__(512) void bucket_scatter_kernel(const void* __restrict__ ei,
                                                             int* __restrict__ bcursor,
                                                             unsigned int* __restrict__ epacked) {
    __shared__ int lcount[NB];
    __shared__ int lcur[NB];
    int tid = threadIdx.x;
    for (int i = tid; i < NB; i += 512) lcount[i] = 0;
    int base = blockIdx.x * EPB;  // NBLK*EPB == NE: no bounds guards needed
    // per-wave dtype detect: int64 staging => odd 32-bit words all zero
    // (node ids are non-negative < 2^31); int32 staging => odd words are
    // node ids, all-zero across 64 samples has prob ~(1e-5)^64 ~ 0.
    unsigned int hw = ((const unsigned int*)ei)[2 * (base + tid) + 1];
    int is64 = (__ballot(hw != 0) == 0ULL);  // wave-uniform
    int r[7], c[7];
    r[6] = -1;
    if (!is64) {
        const int* e32 = (const int*)ei;
#pragma unroll
        for (int k = 0; k < 6; k++) {
            int e = base + k * 512 + tid;
            r[k] = e32[e];
            c[k] = e32[NE + e];
        }
        if (tid < EPB - 6 * 512) {
            int e = base + 6 * 512 + tid;
            r[6] = e32[e];
            c[6] = e32[NE + e];
        }
    } else {
        const long long* e64 = (const long long*)ei;
#pragma unroll
        for (int k = 0; k < 6; k++) {
            int e = base + k * 512 + tid;
            r[k] = (int)e64[e];
            c[k] = (int)e64[(long long)NE + e];
        }
        if (tid < EPB - 6 * 512) {
            int e = base + 6 * 512 + tid;
            r[6] = (int)e64[e];
            c[6] = (int)e64[(long long)NE + e];
        }
    }
    __syncthreads();  // lcount init visible
#pragma unroll
    for (int k = 0; k < 7; k++)
        if (r[k] >= 0) atomicAdd(&lcount[c[k] >> 8], 1);
    __syncthreads();
    // reserve a global slice per touched bucket; lcur = running cursor
    for (int i = tid; i < NB; i += 512) {
        int cnt = lcount[i];
        lcur[i] = (cnt ? atomicAdd(&bcursor[i], cnt) : 0) + i * CAP;
    }
    __syncthreads();
    // direct scattered stores (runs were only ~8 long anyway; grouping+flush
    // bought no coalescing for 2 extra LDS round-trips)
#pragma unroll
    for (int k = 0; k < 7; k++) {
        if (r[k] >= 0) {
            int b = c[k] >> 8;
            int pos = atomicAdd(&lcur[b], 1);
            if (pos < (b + 1) * CAP)  // overflow guard (8-sigma)
                epacked[pos] = ((unsigned)(c[k] & 255) << 24) | (unsigned)r[k];
        }
    }
}

// ---- csr: fold weights + single-read counting sort + meta + fused z ------

__global__ __launch_bounds__(512) void bucket_csr_kernel(
    const unsigned int* __restrict__ epacked, const int* __restrict__ bcount,
    const float* __restrict__ x,
    const float* __restrict__ W1, const float* __restrict__ b1,
    const float* __restrict__ W2, const float* __restrict__ b2,
    const float* __restrict__ W3, const float* __restrict__ b3,
    const float* __restrict__ W4, const float* __restrict__ b4,
    const float* __restrict__ W5, const float* __restrict__ b5,
    float* __restrict__ cv,
    int2* __restrict__ meta, int* __restrict__ srow,
    float4* __restrict__ Ta, int N) {
    __shared__ float w45[96], w345[96], w2345[96];
    __shared__ float4 Wl4[8];
    __shared__ int lcount[256];
    __shared__ int lcur[256];
    __shared__ int wsum[4];
    __shared__ int sbuf[CAP];
    int b = blockIdx.x;
    int tid = threadIdx.x;
    int s0 = b * CAP;
    int cnt = bcount[b];
    if (cnt > CAP) cnt = CAP;
    if (tid < 256) lcount[tid] = 0;
    int i3 = tid / 3, j3 = tid - 3 * (tid / 3);
    if (tid < 96) {
        float s = 0.0f;
        for (int k = 0; k < 32; k++) s += W4[i3 * 32 + k] * W5[k * 3 + j3];
        w45[i3 * 3 + j3] = s;
    }
    __syncthreads();
    // issue the single epacked read early: latency overlaps fold stages
    unsigned int ev[9];
#pragma unroll
    for (int k = 0; k < 9; k++) {
        int i = k * 512 + tid;
        ev[k] = (i < cnt) ? epacked[s0 + i] : 0xFFFFFFFFu;  // sentinel (row>=2^24-1 impossible... row 0xFFFFFF >= NN)
    }
    if (tid < 96) {
        float s = 0.0f;
        for (int k = 0; k < 32; k++) s += W3[i3 * 32 + k] * w45[k * 3 + j3];
        w345[i3 * 3 + j3] = s;
    }
    __syncthreads();
    if (tid < 96) {
        float s = 0.0f;
        for (int k = 0; k < 32; k++) s += W2[i3 * 32 + k] * w345[k * 3 + j3];
        w2345[i3 * 3 + j3] = s;
    }
    __syncthreads();
    if (tid < 32) {
        int ii = tid >> 2, jj = tid & 3;  // 8 x 4
        float s = 0.0f;
        if (jj < 3)
            for (int k = 0; k < 32; k++) s += W1[ii * 32 + k] * w2345[k * 3 + jj];
        ((float*)Wl4)[tid] = s;
    }
    if (b == 0 && tid >= 32 && tid < 52) {  // cv for the prop passes
        int kk = (tid - 32) >> 2, jj = (tid - 32) & 3;
        float s = 0.0f;
        if (jj < 3) {
            if (kk == 0) for (int k = 0; k < 32; k++) s += b1[k] * w2345[k * 3 + jj];
            if (kk == 1) for (int k = 0; k < 32; k++) s += b2[k] * w345[k * 3 + jj];
            if (kk == 2) for (int k = 0; k < 32; k++) s += b3[k] * w45[k * 3 + jj];
            if (kk == 3) for (int k = 0; k < 32; k++) s += b4[k] * W5[k * 3 + jj];
            if (kk == 4) s = b5[jj];
        }
        cv[tid - 32] = s;
    }
    // count (lcount init covered by first barrier; ev in registers)
#pragma unroll
    for (int k = 0; k < 9; k++)
        if (ev[k] != 0xFFFFFFFFu) atomicAdd(&lcount[ev[k] >> 24], 1);
    __syncthreads();
    // exclusive scan over 256 counters via wave shuffles (4 live waves)
    int lane = tid & 63, w = tid >> 6;
    int myc = (tid < 256) ? lcount[tid] : 0;
    int acc = myc;
#pragma unroll
    for (int off = 1; off < 64; off <<= 1) {
        int y = __shfl_up(acc, off);
        if (lane >= off) acc += y;
    }
    if (lane == 63 && w < 4) wsum[w] = acc;
    __syncthreads();
    if (tid == 0) {
        int s = 0;
#pragma unroll
        for (int j = 0; j < 4; j++) { int t = wsum[j]; wsum[j] = s; s += t; }
    }
    __syncthreads();
    if (tid < 256) {
        int excl = acc - myc + wsum[w];
        lcur[tid] = excl;
        int col = (b << 8) + tid;
        if (col < N) {
            meta[col] = make_int2(s0 + excl, myc);
            float d = 1.0f / sqrtf((float)myc + 1.0f);  // +1 self-loop
            // z: t0 = d * (x[col] @ Wt)
            const float4* x4 = (const float4*)x + col * 2;
            float4 av = x4[0], bv = x4[1];
            float xs[8] = {av.x, av.y, av.z, av.w, bv.x, bv.y, bv.z, bv.w};
            float4 o = make_float4(0.f, 0.f, 0.f, 0.f);
#pragma unroll
            for (int k = 0; k < 8; k++) {
                float4 ww = Wl4[k];
                o.x += xs[k] * ww.x; o.y += xs[k] * ww.y; o.z += xs[k] * ww.z;
            }
            o.x *= d; o.y *= d; o.z *= d; o.w = 0.0f;
            Ta[col] = o;
        }
    }
    __syncthreads();
    // place from registers into LDS, then coalesced srow flush
#pragma unroll
    for (int k = 0; k < 9; k++) {
        if (ev[k] != 0xFFFFFFFFu) {
            int p = atomicAdd(&lcur[ev[k] >> 24], 1);
            sbuf[p] = (int)(ev[k] & 0xFFFFFFu);
        }
    }
    __syncthreads();
    for (int i = tid; i < cnt; i += 512) srow[s0 + i] = sbuf[i];
}

// ---- propagation pass: a[c] = t[c] + Σ t[srow];  4 lanes per node --------
//      LAST: out = d*a + c5, else t' = d*d*a + d*ck.  dinv recomputed.

template <bool LAST>
__global__ __launch_bounds__(256) void prop_kernel(
    const int2* __restrict__ meta, const int* __restrict__ srow,
    const float4* __restrict__ tin, const float* __restrict__ cv, int k,
    float4* __restrict__ tout, float* __restrict__ out, int N) {
    int tid = blockIdx.x * 256 + threadIdx.x;
    int c = tid >> 2, q = tid & 3;
    if (c >= N) return;
    int2 m = meta[c];
    int s = m.x;
    int d = m.y;
    float4 a = (q == 0) ? tin[c] : make_float4(0.f, 0.f, 0.f, 0.f);  // self-loop
    float4 a2 = make_float4(0.f, 0.f, 0.f, 0.f);
    int i = q;
    for (; i + 4 < d; i += 8) {
        int r0 = srow[s + i];
        int r1 = srow[s + i + 4];
        float4 v0 = tin[r0];
        float4 v1 = tin[r1];
        a.x += v0.x; a.y += v0.y; a.z += v0.z;
        a2.x += v1.x; a2.y += v1.y; a2.z += v1.z;
    }
    if (i < d) {
        float4 v = tin[srow[s + i]];
        a.x += v.x; a.y += v.y; a.z += v.z;
    }
    a.x += a2.x; a.y += a2.y; a.z += a2.z;
    // combine the 4 lanes of this node
    a.x += __shfl_xor(a.x, 1); a.y += __shfl_xor(a.y, 1); a.z += __shfl_xor(a.z, 1);
    a.x += __shfl_xor(a.x, 2); a.y += __shfl_xor(a.y, 2); a.z += __shfl_xor(a.z, 2);
    if (q == 0) {
        float dd = 1.0f / sqrtf((float)d + 1.0f);
        float cx = cv[k * 4 + 0], cy = cv[k * 4 + 1], cz = cv[k * 4 + 2];
        if (LAST) {
            out[c * 3 + 0] = dd * a.x + cx;
            out[c * 3 + 1] = dd * a.y + cy;
            out[c * 3 + 2] = dd * a.z + cz;
        } else {
            float d2 = dd * dd;
            float4 o;
            o.x = d2 * a.x + dd * cx;
            o.y = d2 * a.y + dd * cy;
            o.z = d2 * a.z + dd * cz;
            o.w = 0.0f;
            tout[c] = o;
        }
    }
}

// ---- launch --------------------------------------------------------------

extern "C" void kernel_launch(void* const* d_in, const int* in_sizes, int n_in,
                              void* d_out, int out_size, void* d_ws, size_t ws_size,
                              hipStream_t stream) {
    const float* x  = (const float*)d_in[0];
    const void*  ei = d_in[1];
    const float* W1 = (const float*)d_in[2];  const float* b1 = (const float*)d_in[3];
    const float* W2 = (const float*)d_in[4];  const float* b2 = (const float*)d_in[5];
    const float* W3 = (const float*)d_in[6];  const float* b3 = (const float*)d_in[7];
    const float* W4 = (const float*)d_in[8];  const float* b4 = (const float*)d_in[9];
    const float* W5 = (const float*)d_in[10]; const float* b5 = (const float*)d_in[11];
    float* out = (float*)d_out;

    char* p = (char*)d_ws;
    auto alloc = [&](size_t bytes) {
        char* r = p;
        p += (bytes + 255) & ~(size_t)255;
        return r;
    };
    int2*  meta    = (int2*)alloc((size_t)NN * 8);
    int*   bcursor = (int*)alloc(NB * 4);
    float* cv      = (float*)alloc(5 * 4 * 4);
    unsigned int* epacked = (unsigned int*)alloc((size_t)NB * CAP * 4);
    int*          srow    = (int*)alloc((size_t)NB * CAP * 4);
    float4*       Ta      = (float4*)alloc((size_t)NN * 16);
    float4*       Tb      = (float4*)alloc((size_t)NN * 16);
    if ((size_t)(p - (char*)d_ws) > ws_size) return;  // canary: zero output

    hipMemsetAsync(bcursor, 0, NB * 4, stream);
    bucket_scatter_kernel<<<NBLK, 512, 0, stream>>>(ei, bcursor, epacked);
    bucket_csr_kernel<<<NB, 512, 0, stream>>>(epacked, bcursor, x,
                                              W1, b1, W2, b2, W3, b3, W4, b4, W5, b5,
                                              cv, meta, srow, Ta, NN);

    // g_k = Â g_{k-1} + 1 c_k^T in folded t = dinv ⊙ g coordinates
    int gP = (NN * 4 + 255) / 256;
    prop_kernel<false><<<gP, 256, 0, stream>>>(meta, srow, Ta, cv, 0, Tb, nullptr, NN);
    prop_kernel<false><<<gP, 256, 0, stream>>>(meta, srow, Tb, cv, 1, Ta, nullptr, NN);
    prop_kernel<false><<<gP, 256, 0, stream>>>(meta, srow, Ta, cv, 2, Tb, nullptr, NN);
    prop_kernel<false><<<gP, 256, 0, stream>>>(meta, srow, Tb, cv, 3, Ta, nullptr, NN);
    prop_kernel<true><<<gP, 256, 0, stream>>>(meta, srow, Ta, cv, 4, nullptr, out, NN);
}

// Round 4
// 171.024 us; speedup vs baseline: 1.7644x; 1.0133x over previous
//
#include <hip/hip_runtime.h>

#define NN 100000
#define NE 1600000
#define NB 391        // ceil(NN/256) buckets, bucket = col >> 8
#define EPB 3125      // edges per block in scatter: 512 blocks x 3125 = NE exactly
#define NBLK 512
#define CAP 5632      // bucket capacity: 8-sigma count (4604) + 4-align padding (<=768)
#define RCAP 4608     // 9*512: max edges READ per bucket (8-sigma on true count)

// NOTE (r10/r12): intra-kernel grid-wide barriers cost ~120 µs on gfx950. Split dispatches.
// NOTE (r1): block-count rounding is NOT a sink (3-4 blocks/CU co-schedule).
// NOTE (r2): unsorted-edge prop via LDS float atomics is +27 µs/pass WORSE than CSR+shuffle.
// NOTE (r3): deleting prep/second epacked read/grouped flush = NEUTRAL -> prop passes +
// fixed overhead dominate. This round: 4-aligned CSR segments, sentinel row NN
// (tin[NN]=0), int4 srow loads -> 4 independent gathers/lane (MLP 2->4, rounds /4).

// ---- scatter: count -> reserve -> direct scattered store -----------------
// epacked[i] = (col&255)<<24 | row (row < 2^24); bucket regions fixed CAP.
// bcursor[b] holds COUNT (base b*CAP added locally); memset to 0 before.

__global__ __launch_bounds__(512) void bucket_scatter_kernel(const void* __restrict__ ei,
                                                             int* __restrict__ bcursor,
                                                             unsigned int* __restrict__ epacked) {
    __shared__ int lcount[NB];
    __shared__ int lcur[NB];
    int tid = threadIdx.x;
    for (int i = tid; i < NB; i += 512) lcount[i] = 0;
    int base = blockIdx.x * EPB;  // NBLK*EPB == NE: no bounds guards needed
    // per-wave dtype detect: int64 staging => odd 32-bit words all zero
    unsigned int hw = ((const unsigned int*)ei)[2 * (base + tid) + 1];
    int is64 = (__ballot(hw != 0) == 0ULL);  // wave-uniform
    int r[7], c[7];
    r[6] = -1;
    if (!is64) {
        const int* e32 = (const int*)ei;
#pragma unroll
        for (int k = 0; k < 6; k++) {
            int e = base + k * 512 + tid;
            r[k] = e32[e];
            c[k] = e32[NE + e];
        }
        if (tid < EPB - 6 * 512) {
            int e = base + 6 * 512 + tid;
            r[6] = e32[e];
            c[6] = e32[NE + e];
        }
    } else {
        const long long* e64 = (const long long*)ei;
#pragma unroll
        for (int k = 0; k < 6; k++) {
            int e = base + k * 512 + tid;
            r[k] = (int)e64[e];
            c[k] = (int)e64[(long long)NE + e];
        }
        if (tid < EPB - 6 * 512) {
            int e = base + 6 * 512 + tid;
            r[6] = (int)e64[e];
            c[6] = (int)e64[(long long)NE + e];
        }
    }
    __syncthreads();  // lcount init visible
#pragma unroll
    for (int k = 0; k < 7; k++)
        if (r[k] >= 0) atomicAdd(&lcount[c[k] >> 8], 1);
    __syncthreads();
    // reserve a global slice per touched bucket; lcur = running cursor
    for (int i = tid; i < NB; i += 512) {
        int cnt = lcount[i];
        lcur[i] = (cnt ? atomicAdd(&bcursor[i], cnt) : 0) + i * CAP;
    }
    __syncthreads();
#pragma unroll
    for (int k = 0; k < 7; k++) {
        if (r[k] >= 0) {
            int b = c[k] >> 8;
            int pos = atomicAdd(&lcur[b], 1);
            if (pos < b * CAP + RCAP)  // overflow guard (8-sigma)
                epacked[pos] = ((unsigned)(c[k] & 255) << 24) | (unsigned)r[k];
        }
    }
}

// ---- csr: fold weights + single-read counting sort (4-aligned segments) --

__global__ __launch_bounds__(512) void bucket_csr_kernel(
    const unsigned int* __restrict__ epacked, const int* __restrict__ bcount,
    const float* __restrict__ x,
    const float* __restrict__ W1, const float* __restrict__ b1,
    const float* __restrict__ W2, const float* __restrict__ b2,
    const float* __restrict__ W3, const float* __restrict__ b3,
    const float* __restrict__ W4, const float* __restrict__ b4,
    const float* __restrict__ W5, const float* __restrict__ b5,
    float* __restrict__ cv,
    int2* __restrict__ meta, int* __restrict__ srow,
    float4* __restrict__ Ta, float4* __restrict__ Tb, int N) {
    __shared__ float w45[96], w345[96], w2345[96];
    __shared__ float4 Wl4[8];
    __shared__ int lcount[256];
    __shared__ int lcur[256];
    __shared__ int wsum[4];
    __shared__ int ptot;
    __shared__ int sbuf[CAP];
    int b = blockIdx.x;
    int tid = threadIdx.x;
    int s0 = b * CAP;
    int cnt = bcount[b];
    if (cnt > RCAP) cnt = RCAP;
    if (tid < 256) lcount[tid] = 0;
    for (int i = tid; i < CAP; i += 512) sbuf[i] = NN;  // sentinel pad (tin[NN]=0)
    int i3 = tid / 3, j3 = tid - 3 * (tid / 3);
    if (tid < 96) {
        float s = 0.0f;
        for (int k = 0; k < 32; k++) s += W4[i3 * 32 + k] * W5[k * 3 + j3];
        w45[i3 * 3 + j3] = s;
    }
    __syncthreads();
    // single epacked read, issued early: latency overlaps fold stages
    unsigned int ev[9];
#pragma unroll
    for (int k = 0; k < 9; k++) {
        int i = k * 512 + tid;
        ev[k] = (i < cnt) ? epacked[s0 + i] : 0xFFFFFFFFu;
    }
    if (tid < 96) {
        float s = 0.0f;
        for (int k = 0; k < 32; k++) s += W3[i3 * 32 + k] * w45[k * 3 + j3];
        w345[i3 * 3 + j3] = s;
    }
    __syncthreads();
    if (tid < 96) {
        float s = 0.0f;
        for (int k = 0; k < 32; k++) s += W2[i3 * 32 + k] * w345[k * 3 + j3];
        w2345[i3 * 3 + j3] = s;
    }
    __syncthreads();
    if (tid < 32) {
        int ii = tid >> 2, jj = tid & 3;  // 8 x 4
        float s = 0.0f;
        if (jj < 3)
            for (int k = 0; k < 32; k++) s += W1[ii * 32 + k] * w2345[k * 3 + jj];
        ((float*)Wl4)[tid] = s;
    }
    if (b == 0 && tid >= 32 && tid < 52) {  // cv for the prop passes
        int kk = (tid - 32) >> 2, jj = (tid - 32) & 3;
        float s = 0.0f;
        if (jj < 3) {
            if (kk == 0) for (int k = 0; k < 32; k++) s += b1[k] * w2345[k * 3 + jj];
            if (kk == 1) for (int k = 0; k < 32; k++) s += b2[k] * w345[k * 3 + jj];
            if (kk == 2) for (int k = 0; k < 32; k++) s += b3[k] * w45[k * 3 + jj];
            if (kk == 3) for (int k = 0; k < 32; k++) s += b4[k] * W5[k * 3 + jj];
            if (kk == 4) s = b5[jj];
        }
        cv[tid - 32] = s;
    }
    if (b == 0 && tid == 52) {  // sentinel entries for pad gathers
        Ta[NN] = make_float4(0.f, 0.f, 0.f, 0.f);
        Tb[NN] = make_float4(0.f, 0.f, 0.f, 0.f);
    }
#pragma unroll
    for (int k = 0; k < 9; k++)
        if (ev[k] != 0xFFFFFFFFu) atomicAdd(&lcount[ev[k] >> 24], 1);
    __syncthreads();
    // exclusive scan over 4-ROUNDED counts via wave shuffles (4 live waves)
    int lane = tid & 63, w = tid >> 6;
    int myc = (tid < 256) ? lcount[tid] : 0;
    int myp = (myc + 3) & ~3;  // 16B-aligned segment size
    int acc = myp;
#pragma unroll
    for (int off = 1; off < 64; off <<= 1) {
        int y = __shfl_up(acc, off);
        if (lane >= off) acc += y;
    }
    if (lane == 63 && w < 4) wsum[w] = acc;
    __syncthreads();
    if (tid == 0) {
        int s = 0;
#pragma unroll
        for (int j = 0; j < 4; j++) { int t = wsum[j]; wsum[j] = s; s += t; }
    }
    __syncthreads();
    if (tid < 256) {
        int excl = acc - myp + wsum[w];
        lcur[tid] = excl;
        if (tid == 255) ptot = excl + myp;
        int col = (b << 8) + tid;
        if (col < N) {
            meta[col] = make_int2(s0 + excl, myc);
            float d = 1.0f / sqrtf((float)myc + 1.0f);  // +1 self-loop
            // z: t0 = d * (x[col] @ Wt)
            const float4* x4 = (const float4*)x + col * 2;
            float4 av = x4[0], bv = x4[1];
            float xs[8] = {av.x, av.y, av.z, av.w, bv.x, bv.y, bv.z, bv.w};
            float4 o = make_float4(0.f, 0.f, 0.f, 0.f);
#pragma unroll
            for (int k = 0; k < 8; k++) {
                float4 ww = Wl4[k];
                o.x += xs[k] * ww.x; o.y += xs[k] * ww.y; o.z += xs[k] * ww.z;
            }
            o.x *= d; o.y *= d; o.z *= d; o.w = 0.0f;
            Ta[col] = o;
        }
    }
    __syncthreads();
    // place from registers into LDS (pads remain sentinel), coalesced flush
#pragma unroll
    for (int k = 0; k < 9; k++) {
        if (ev[k] != 0xFFFFFFFFu) {
            int p = atomicAdd(&lcur[ev[k] >> 24], 1);
            sbuf[p] = (int)(ev[k] & 0xFFFFFFu);
        }
    }
    __syncthreads();
    int pt = ptot;
    for (int i = tid; i < pt; i += 512) srow[s0 + i] = sbuf[i];
}

// ---- propagation: 4 lanes/node, int4 srow load -> 4 independent gathers --
//      a[c] = t[c] + Σ t[srow];  LAST: out = d*a + c5, else t' = d*d*a + d*ck.

template <bool LAST>
__global__ __launch_bounds__(256) void prop_kernel(
    const int2* __restrict__ meta, const int* __restrict__ srow,
    const float4* __restrict__ tin, const float* __restrict__ cv, int k,
    float4* __restrict__ tout, float* __restrict__ out, int N) {
    int tid = blockIdx.x * 256 + threadIdx.x;
    int c = tid >> 2, q = tid & 3;
    if (c >= N) return;
    int2 m = meta[c];
    int s = m.x;
    int d = m.y;
    int dpad = (d + 3) & ~3;
    float ax = 0.f, ay = 0.f, az = 0.f;
    if (q == 0) { float4 t = tin[c]; ax = t.x; ay = t.y; az = t.z; }  // self-loop
    float bx = 0.f, by = 0.f, bz = 0.f;
    float cx = 0.f, cy = 0.f, cz = 0.f;
    float dx = 0.f, dy = 0.f, dz = 0.f;
    for (int j = 4 * q; j < dpad; j += 16) {
        int4 rr = *(const int4*)(srow + s + j);   // 16B-aligned (segments 4-aligned)
        float4 v0 = tin[rr.x];                     // 4 independent gathers
        float4 v1 = tin[rr.y];
        float4 v2 = tin[rr.z];
        float4 v3 = tin[rr.w];
        ax += v0.x; ay += v0.y; az += v0.z;
        bx += v1.x; by += v1.y; bz += v1.z;
        cx += v2.x; cy += v2.y; cz += v2.z;
        dx += v3.x; dy += v3.y; dz += v3.z;
    }
    ax += bx + cx + dx;
    ay += by + cy + dy;
    az += bz + cz + dz;
    // combine the 4 lanes of this node
    ax += __shfl_xor(ax, 1); ay += __shfl_xor(ay, 1); az += __shfl_xor(az, 1);
    ax += __shfl_xor(ax, 2); ay += __shfl_xor(ay, 2); az += __shfl_xor(az, 2);
    if (q == 0) {
        float dd = 1.0f / sqrtf((float)d + 1.0f);
        float vx = cv[k * 4 + 0], vy = cv[k * 4 + 1], vz = cv[k * 4 + 2];
        if (LAST) {
            out[c * 3 + 0] = dd * ax + vx;
            out[c * 3 + 1] = dd * ay + vy;
            out[c * 3 + 2] = dd * az + vz;
        } else {
            float d2 = dd * dd;
            float4 o;
            o.x = d2 * ax + dd * vx;
            o.y = d2 * ay + dd * vy;
            o.z = d2 * az + dd * vz;
            o.w = 0.0f;
            tout[c] = o;
        }
    }
}

// ---- launch --------------------------------------------------------------

extern "C" void kernel_launch(void* const* d_in, const int* in_sizes, int n_in,
                              void* d_out, int out_size, void* d_ws, size_t ws_size,
                              hipStream_t stream) {
    const float* x  = (const float*)d_in[0];
    const void*  ei = d_in[1];
    const float* W1 = (const float*)d_in[2];  const float* b1 = (const float*)d_in[3];
    const float* W2 = (const float*)d_in[4];  const float* b2 = (const float*)d_in[5];
    const float* W3 = (const float*)d_in[6];  const float* b3 = (const float*)d_in[7];
    const float* W4 = (const float*)d_in[8];  const float* b4 = (const float*)d_in[9];
    const float* W5 = (const float*)d_in[10]; const float* b5 = (const float*)d_in[11];
    float* out = (float*)d_out;

    char* p = (char*)d_ws;
    auto alloc = [&](size_t bytes) {
        char* r = p;
        p += (bytes + 255) & ~(size_t)255;
        return r;
    };
    int2*  meta    = (int2*)alloc((size_t)NN * 8);
    int*   bcursor = (int*)alloc(NB * 4);
    float* cv      = (float*)alloc(5 * 4 * 4);
    unsigned int* epacked = (unsigned int*)alloc((size_t)NB * CAP * 4);
    int*          srow    = (int*)alloc((size_t)NB * CAP * 4);
    float4*       Ta      = (float4*)alloc((size_t)(NN + 1) * 16);
    float4*       Tb      = (float4*)alloc((size_t)(NN + 1) * 16);
    if ((size_t)(p - (char*)d_ws) > ws_size) return;  // canary: zero output

    hipMemsetAsync(bcursor, 0, NB * 4, stream);
    bucket_scatter_kernel<<<NBLK, 512, 0, stream>>>(ei, bcursor, epacked);
    bucket_csr_kernel<<<NB, 512, 0, stream>>>(epacked, bcursor, x,
                                              W1, b1, W2, b2, W3, b3, W4, b4, W5, b5,
                                              cv, meta, srow, Ta, Tb, NN);

    // g_k = Â g_{k-1} + 1 c_k^T in folded t = dinv ⊙ g coordinates
    int gP = (NN * 4 + 255) / 256;
    prop_kernel<false><<<gP, 256, 0, stream>>>(meta, srow, Ta, cv, 0, Tb, nullptr, NN);
    prop_kernel<false><<<gP, 256, 0, stream>>>(meta, srow, Tb, cv, 1, Ta, nullptr, NN);
    prop_kernel<false><<<gP, 256, 0, stream>>>(meta, srow, Ta, cv, 2, Tb, nullptr, NN);
    prop_kernel<false><<<gP, 256, 0, stream>>>(meta, srow, Tb, cv, 3, Ta, nullptr, NN);
    prop_kernel<true><<<gP, 256, 0, stream>>>(meta, srow, Ta, cv, 4, nullptr, out, NN);
}

// Round 5
// 170.557 us; speedup vs baseline: 1.7692x; 1.0027x over previous
//
#include <hip/hip_runtime.h>

#define NN 100000
#define NE 1600000
#define NB 391        // ceil(NN/256) buckets, bucket = col >> 8
#define EPB 3125      // edges per block in scatter: 512 blocks x 3125 = NE exactly
#define NBLK 512
#define CAP 5632      // srow bucket capacity: 8-sigma count (4604) + 4-align pad (<=768)
#define RCAP 4608     // max edges processed per bucket (8-sigma on true count)

// NOTE (r10/r12): intra-kernel grid-wide barriers cost ~120 µs on gfx950. Split dispatches.
// NOTE (r1): block-count rounding is NOT a sink (3-4 blocks/CU co-schedule).
// NOTE (r2): unsorted-edge prop via LDS float atomics is +27 µs/pass WORSE than CSR+shuffle.
// NOTE (r3,r4): deleting prep / second epacked read / 2x prop MLP = ALL NEUTRAL.
// Model: timed window = 2x 256MiB harness fills (~84 µs) + ~9 dispatch gaps + ~60 µs
// of thin kernels. Only >10 µs structural changes are visible.
// This round: atomic-free sort. Scatter: LDS-sort per block -> CONTIGUOUS flush to
// per-block region + per-(bucket,block) count/start tables (no global atomics, no
// memset dispatch). CSR: gather 512 short runs per bucket (L1-resident), sort as
// before. Props untouched (512-thr blocks). 9 -> 7 dispatches.

// ---- scatter: per-block LDS bucket-sort, contiguous flush ----------------
// gslot[blk*EPB + i] = block blk's edges grouped by bucket; packed
// (col&255)<<24 | row.  cntT[b*NBLK+blk] / startT[b*NBLK+blk] = run of
// bucket b inside block blk.

__global__ __launch_bounds__(512) void bucket_scatter_kernel(const void* __restrict__ ei,
                                                             unsigned int* __restrict__ gslot,
                                                             int* __restrict__ cntT,
                                                             int* __restrict__ startT) {
    __shared__ int lcount[NB];
    __shared__ int lstart[NB];
    __shared__ int lcur[NB];
    __shared__ int wsum[8];
    __shared__ unsigned int slotv[EPB];
    int tid = threadIdx.x;
    for (int i = tid; i < NB; i += 512) lcount[i] = 0;
    int base = blockIdx.x * EPB;  // NBLK*EPB == NE: no bounds guards needed
    // per-wave dtype detect: int64 staging => odd 32-bit words all zero
    unsigned int hw = ((const unsigned int*)ei)[2 * (base + tid) + 1];
    int is64 = (__ballot(hw != 0) == 0ULL);  // wave-uniform
    int r[7], c[7];
    r[6] = -1;
    if (!is64) {
        const int* e32 = (const int*)ei;
#pragma unroll
        for (int k = 0; k < 6; k++) {
            int e = base + k * 512 + tid;
            r[k] = e32[e];
            c[k] = e32[NE + e];
        }
        if (tid < EPB - 6 * 512) {
            int e = base + 6 * 512 + tid;
            r[6] = e32[e];
            c[6] = e32[NE + e];
        }
    } else {
        const long long* e64 = (const long long*)ei;
#pragma unroll
        for (int k = 0; k < 6; k++) {
            int e = base + k * 512 + tid;
            r[k] = (int)e64[e];
            c[k] = (int)e64[(long long)NE + e];
        }
        if (tid < EPB - 6 * 512) {
            int e = base + 6 * 512 + tid;
            r[6] = (int)e64[e];
            c[6] = (int)e64[(long long)NE + e];
        }
    }
    __syncthreads();  // lcount init visible
#pragma unroll
    for (int k = 0; k < 7; k++)
        if (r[k] >= 0) atomicAdd(&lcount[c[k] >> 8], 1);
    __syncthreads();
    // exclusive scan of lcount over 512-wide via wave shuffles (8 waves)
    int lane = tid & 63, w = tid >> 6;
    int v = (tid < NB) ? lcount[tid] : 0;
    int acc = v;
#pragma unroll
    for (int off = 1; off < 64; off <<= 1) {
        int y = __shfl_up(acc, off);
        if (lane >= off) acc += y;
    }
    if (lane == 63) wsum[w] = acc;
    __syncthreads();
    if (tid == 0) {
        int s = 0;
#pragma unroll
        for (int j = 0; j < 8; j++) { int t = wsum[j]; wsum[j] = s; s += t; }
    }
    __syncthreads();
    acc += wsum[w];
    if (tid < NB) {
        int excl = acc - v;
        lstart[tid] = excl;
        lcur[tid] = excl;
    }
    __syncthreads();
    // group edges by bucket in LDS
#pragma unroll
    for (int k = 0; k < 7; k++) {
        if (r[k] >= 0) {
            int pos = atomicAdd(&lcur[c[k] >> 8], 1);
            slotv[pos] = ((unsigned)(c[k] & 255) << 24) | (unsigned)r[k];
        }
    }
    __syncthreads();
    // contiguous flush + per-(bucket,block) metadata (L2 write-combined)
    for (int i = tid; i < EPB; i += 512) gslot[base + i] = slotv[i];
    for (int i = tid; i < NB; i += 512) {
        cntT[i * NBLK + blockIdx.x] = lcount[i];
        startT[i * NBLK + blockIdx.x] = lstart[i];
    }
}

// ---- csr: run-gather + fold weights + counting sort (4-aligned segs) -----

__global__ __launch_bounds__(512) void bucket_csr_kernel(
    const unsigned int* __restrict__ gslot,
    const int* __restrict__ cntT, const int* __restrict__ startT,
    const float* __restrict__ x,
    const float* __restrict__ W1, const float* __restrict__ b1,
    const float* __restrict__ W2, const float* __restrict__ b2,
    const float* __restrict__ W3, const float* __restrict__ b3,
    const float* __restrict__ W4, const float* __restrict__ b4,
    const float* __restrict__ W5, const float* __restrict__ b5,
    float* __restrict__ cv,
    int2* __restrict__ meta, int* __restrict__ srow,
    float4* __restrict__ Ta, float4* __restrict__ Tb, int N) {
    __shared__ float w45[96], w345[96], w2345[96];
    __shared__ float4 Wl4[8];
    __shared__ int lcount[256];
    __shared__ int lcur[256];
    __shared__ int wsum[8];
    __shared__ int stot, ptot;
    __shared__ unsigned int sbufraw[RCAP];
    __shared__ int sbuf2[CAP];
    int b = blockIdx.x;
    int tid = threadIdx.x;
    int s0 = b * CAP;
    if (tid < 256) lcount[tid] = 0;
    for (int i = tid; i < CAP; i += 512) sbuf2[i] = NN;  // sentinel pad (tin[NN]=0)
    // my run of bucket b inside scatter-block tid
    int rc = cntT[b * NBLK + tid];
    int rs = startT[b * NBLK + tid];
    // exclusive scan of run counts over 512 (8 waves)
    int lane = tid & 63, w = tid >> 6;
    int acc = rc;
#pragma unroll
    for (int off = 1; off < 64; off <<= 1) {
        int y = __shfl_up(acc, off);
        if (lane >= off) acc += y;
    }
    if (lane == 63) wsum[w] = acc;
    __syncthreads();
    if (tid == 0) {
        int s = 0;
#pragma unroll
        for (int j = 0; j < 8; j++) { int t = wsum[j]; wsum[j] = s; s += t; }
    }
    __syncthreads();
    acc += wsum[w];
    int roff = acc - rc;
    if (tid == 511) stot = roff + rc;
    // run-gather: runs are short (~8), wave's lines are L1-resident
    const unsigned int* src = gslot + (size_t)tid * EPB + rs;
    for (int j = 0; j < rc; j++) {
        int p = roff + j;
        if (p < RCAP) sbufraw[p] = src[j];
    }
    // weight folding (overlaps other waves' gathers)
    int i3 = tid / 3, j3 = tid - 3 * (tid / 3);
    if (tid < 96) {
        float s = 0.0f;
        for (int k = 0; k < 32; k++) s += W4[i3 * 32 + k] * W5[k * 3 + j3];
        w45[i3 * 3 + j3] = s;
    }
    __syncthreads();
    if (tid < 96) {
        float s = 0.0f;
        for (int k = 0; k < 32; k++) s += W3[i3 * 32 + k] * w45[k * 3 + j3];
        w345[i3 * 3 + j3] = s;
    }
    __syncthreads();
    if (tid < 96) {
        float s = 0.0f;
        for (int k = 0; k < 32; k++) s += W2[i3 * 32 + k] * w345[k * 3 + j3];
        w2345[i3 * 3 + j3] = s;
    }
    __syncthreads();
    if (tid < 32) {
        int ii = tid >> 2, jj = tid & 3;  // 8 x 4
        float s = 0.0f;
        if (jj < 3)
            for (int k = 0; k < 32; k++) s += W1[ii * 32 + k] * w2345[k * 3 + jj];
        ((float*)Wl4)[tid] = s;
    }
    if (b == 0 && tid >= 32 && tid < 52) {  // cv for the prop passes
        int kk = (tid - 32) >> 2, jj = (tid - 32) & 3;
        float s = 0.0f;
        if (jj < 3) {
            if (kk == 0) for (int k = 0; k < 32; k++) s += b1[k] * w2345[k * 3 + jj];
            if (kk == 1) for (int k = 0; k < 32; k++) s += b2[k] * w345[k * 3 + jj];
            if (kk == 2) for (int k = 0; k < 32; k++) s += b3[k] * w45[k * 3 + jj];
            if (kk == 3) for (int k = 0; k < 32; k++) s += b4[k] * W5[k * 3 + jj];
            if (kk == 4) s = b5[jj];
        }
        cv[tid - 32] = s;
    }
    if (b == 0 && tid == 52) {  // sentinel entries for pad gathers
        Ta[NN] = make_float4(0.f, 0.f, 0.f, 0.f);
        Tb[NN] = make_float4(0.f, 0.f, 0.f, 0.f);
    }
    __syncthreads();  // sbufraw complete (all gathers before prior barriers in
                      // program order per-thread; this one orders the last stage)
    int cnt = stot;
    if (cnt > RCAP) cnt = RCAP;
    for (int i = tid; i < cnt; i += 512)
        atomicAdd(&lcount[sbufraw[i] >> 24], 1);
    __syncthreads();
    // exclusive scan over 4-ROUNDED counts (4 live waves)
    int myc = (tid < 256) ? lcount[tid] : 0;
    int myp = (myc + 3) & ~3;  // 16B-aligned segment size
    acc = myp;
#pragma unroll
    for (int off = 1; off < 64; off <<= 1) {
        int y = __shfl_up(acc, off);
        if (lane >= off) acc += y;
    }
    if (lane == 63 && w < 4) wsum[w] = acc;
    __syncthreads();
    if (tid == 0) {
        int s = 0;
#pragma unroll
        for (int j = 0; j < 4; j++) { int t = wsum[j]; wsum[j] = s; s += t; }
    }
    __syncthreads();
    if (tid < 256) {
        int excl = acc - myp + wsum[w];
        lcur[tid] = excl;
        if (tid == 255) ptot = excl + myp;
        int col = (b << 8) + tid;
        if (col < N) {
            meta[col] = make_int2(s0 + excl, myc);
            float d = 1.0f / sqrtf((float)myc + 1.0f);  // +1 self-loop
            // z: t0 = d * (x[col] @ Wt)
            const float4* x4 = (const float4*)x + col * 2;
            float4 av = x4[0], bv = x4[1];
            float xs[8] = {av.x, av.y, av.z, av.w, bv.x, bv.y, bv.z, bv.w};
            float4 o = make_float4(0.f, 0.f, 0.f, 0.f);
#pragma unroll
            for (int k = 0; k < 8; k++) {
                float4 ww = Wl4[k];
                o.x += xs[k] * ww.x; o.y += xs[k] * ww.y; o.z += xs[k] * ww.z;
            }
            o.x *= d; o.y *= d; o.z *= d; o.w = 0.0f;
            Ta[col] = o;
        }
    }
    __syncthreads();
    // place (pads remain sentinel), then coalesced flush
    for (int i = tid; i < cnt; i += 512) {
        unsigned int vv = sbufraw[i];
        int p = atomicAdd(&lcur[vv >> 24], 1);
        sbuf2[p] = (int)(vv & 0xFFFFFFu);
    }
    __syncthreads();
    int pt = ptot;
    for (int i = tid; i < pt; i += 512) srow[s0 + i] = sbuf2[i];
}

// ---- propagation: 4 lanes/node, int4 srow load -> 4 independent gathers --
//      a[c] = t[c] + Σ t[srow];  LAST: out = d*a + c5, else t' = d*d*a + d*ck.

template <bool LAST>
__global__ __launch_bounds__(512) void prop_kernel(
    const int2* __restrict__ meta, const int* __restrict__ srow,
    const float4* __restrict__ tin, const float* __restrict__ cv, int k,
    float4* __restrict__ tout, float* __restrict__ out, int N) {
    int tid = blockIdx.x * 512 + threadIdx.x;
    int c = tid >> 2, q = tid & 3;
    if (c >= N) return;
    int2 m = meta[c];
    int s = m.x;
    int d = m.y;
    int dpad = (d + 3) & ~3;
    float ax = 0.f, ay = 0.f, az = 0.f;
    if (q == 0) { float4 t = tin[c]; ax = t.x; ay = t.y; az = t.z; }  // self-loop
    float bx = 0.f, by = 0.f, bz = 0.f;
    float cx = 0.f, cy = 0.f, cz = 0.f;
    float dx = 0.f, dy = 0.f, dz = 0.f;
    for (int j = 4 * q; j < dpad; j += 16) {
        int4 rr = *(const int4*)(srow + s + j);   // 16B-aligned (segments 4-aligned)
        float4 v0 = tin[rr.x];                     // 4 independent gathers
        float4 v1 = tin[rr.y];
        float4 v2 = tin[rr.z];
        float4 v3 = tin[rr.w];
        ax += v0.x; ay += v0.y; az += v0.z;
        bx += v1.x; by += v1.y; bz += v1.z;
        cx += v2.x; cy += v2.y; cz += v2.z;
        dx += v3.x; dy += v3.y; dz += v3.z;
    }
    ax += bx + cx + dx;
    ay += by + cy + dy;
    az += bz + cz + dz;
    // combine the 4 lanes of this node
    ax += __shfl_xor(ax, 1); ay += __shfl_xor(ay, 1); az += __shfl_xor(az, 1);
    ax += __shfl_xor(ax, 2); ay += __shfl_xor(ay, 2); az += __shfl_xor(az, 2);
    if (q == 0) {
        float dd = 1.0f / sqrtf((float)d + 1.0f);
        float vx = cv[k * 4 + 0], vy = cv[k * 4 + 1], vz = cv[k * 4 + 2];
        if (LAST) {
            out[c * 3 + 0] = dd * ax + vx;
            out[c * 3 + 1] = dd * ay + vy;
            out[c * 3 + 2] = dd * az + vz;
        } else {
            float d2 = dd * dd;
            float4 o;
            o.x = d2 * ax + dd * vx;
            o.y = d2 * ay + dd * vy;
            o.z = d2 * az + dd * vz;
            o.w = 0.0f;
            tout[c] = o;
        }
    }
}

// ---- launch --------------------------------------------------------------

extern "C" void kernel_launch(void* const* d_in, const int* in_sizes, int n_in,
                              void* d_out, int out_size, void* d_ws, size_t ws_size,
                              hipStream_t stream) {
    const float* x  = (const float*)d_in[0];
    const void*  ei = d_in[1];
    const float* W1 = (const float*)d_in[2];  const float* b1 = (const float*)d_in[3];
    const float* W2 = (const float*)d_in[4];  const float* b2 = (const float*)d_in[5];
    const float* W3 = (const float*)d_in[6];  const float* b3 = (const float*)d_in[7];
    const float* W4 = (const float*)d_in[8];  const float* b4 = (const float*)d_in[9];
    const float* W5 = (const float*)d_in[10]; const float* b5 = (const float*)d_in[11];
    float* out = (float*)d_out;

    char* p = (char*)d_ws;
    auto alloc = [&](size_t bytes) {
        char* r = p;
        p += (bytes + 255) & ~(size_t)255;
        return r;
    };
    int2*  meta    = (int2*)alloc((size_t)NN * 8);
    float* cv      = (float*)alloc(5 * 4 * 4);
    unsigned int* gslot = (unsigned int*)alloc((size_t)NE * 4);
    int*   cntT    = (int*)alloc((size_t)NB * NBLK * 4);
    int*   startT  = (int*)alloc((size_t)NB * NBLK * 4);
    int*   srow    = (int*)alloc((size_t)NB * CAP * 4);
    float4* Ta     = (float4*)alloc((size_t)(NN + 1) * 16);
    float4* Tb     = (float4*)alloc((size_t)(NN + 1) * 16);
    if ((size_t)(p - (char*)d_ws) > ws_size) return;  // canary: zero output

    bucket_scatter_kernel<<<NBLK, 512, 0, stream>>>(ei, gslot, cntT, startT);
    bucket_csr_kernel<<<NB, 512, 0, stream>>>(gslot, cntT, startT, x,
                                              W1, b1, W2, b2, W3, b3, W4, b4, W5, b5,
                                              cv, meta, srow, Ta, Tb, NN);

    // g_k = Â g_{k-1} + 1 c_k^T in folded t = dinv ⊙ g coordinates
    int gP = (NN * 4 + 511) / 512;
    prop_kernel<false><<<gP, 512, 0, stream>>>(meta, srow, Ta, cv, 0, Tb, nullptr, NN);
    prop_kernel<false><<<gP, 512, 0, stream>>>(meta, srow, Tb, cv, 1, Ta, nullptr, NN);
    prop_kernel<false><<<gP, 512, 0, stream>>>(meta, srow, Ta, cv, 2, Tb, nullptr, NN);
    prop_kernel<false><<<gP, 512, 0, stream>>>(meta, srow, Tb, cv, 3, Ta, nullptr, NN);
    prop_kernel<true><<<gP, 512, 0, stream>>>(meta, srow, Ta, cv, 4, nullptr, out, NN);
}